// Round 18
// baseline (521.426 us; speedup 1.0000x reference)
//
#include <hip/hip_runtime.h>
#include <cfloat>
#include <cmath>

#define D 128
#define N_ATOMS 200000
#define E_ATOMS 800000
#define G_GROUPS 2000
#define N_BIG 7000
#define E_BIG 200000
#define N_ALL (N_ATOMS + N_BIG)
#define E_ALL (E_ATOMS + E_BIG)

static inline int ceil_div(int a, int b) { return (a + b - 1) / b; }

typedef __attribute__((ext_vector_type(8))) _Float16 f16x8;
typedef __attribute__((ext_vector_type(2))) _Float16 h2_t;
typedef __attribute__((ext_vector_type(4))) float f32x4;

__device__ inline h2_t u2h(unsigned u) { return __builtin_bit_cast(h2_t, u); }
__device__ inline unsigned h2u(h2_t h) { return __builtin_bit_cast(unsigned, h); }
__device__ inline unsigned packh2(float x, float y) {
  h2_t h;
  h[0] = (_Float16)x;
  h[1] = (_Float16)y;
  return h2u(h);
}
__device__ inline float leaky(float e) { return fmaxf(e, 0.2f * e); }
__device__ inline float fast_tanh(float x) {
  float cx = fminf(fmaxf(x, -15.f), 15.f);
  float t = __expf(2.f * cx);
  return (t - 1.f) * __frcp_rn(t + 1.f);
}

// ---------------- CSR build (both graphs merged, rank-based, atomic only in count) --------
__global__ void count_all(const int* __restrict__ adst, const int* __restrict__ ddst, int* __restrict__ deg,
                          int* __restrict__ rank) {
  int i = blockIdx.x * 256 + threadIdx.x;
  if (i < E_ATOMS)
    rank[i] = atomicAdd(&deg[adst[i]], 1);
  else if (i < E_ALL)
    rank[i] = atomicAdd(&deg[N_ATOMS + ddst[i - E_ATOMS]], 1);
}

__global__ void fill_csx(const int* __restrict__ asrc, const int* __restrict__ adst,
                         const int* __restrict__ dsrc, const int* __restrict__ ddst,
                         const int* __restrict__ rpx, const int* __restrict__ rank, int* __restrict__ csx) {
  int i = blockIdx.x * 256 + threadIdx.x;
  if (i < E_ATOMS) {
    csx[rpx[adst[i]] + rank[i]] = asrc[i];
  } else if (i < E_ALL) {
    int k = i - E_ATOMS;
    csx[rpx[N_ATOMS + ddst[k]] + rank[i]] = dsrc[k];
  }
}

// self entry + pad entries (src = self) for every node
__global__ void fill_pad(const int* __restrict__ deg, const int* __restrict__ rpx, int* __restrict__ csx) {
  int d = blockIdx.x * 256 + threadIdx.x;
  if (d >= N_ALL) return;
  int dg = deg[d];
  int b = rpx[d], e = rpx[d + 1];
  int sv = (d < N_ATOMS) ? d : d - N_ATOMS;  // big-graph srcs are local indices
  for (int j = b + dg; j < e; ++j) csx[j] = sv;
}

// cntp for all nodes + dis for big-graph nodes (merged)
__global__ void post_count(const int* __restrict__ deg, int* __restrict__ cntp, float* __restrict__ dis) {
  int i = blockIdx.x * 256 + threadIdx.x;
  if (i < N_ALL) cntp[i] = (deg[i] + 8) & ~7;  // (deg + 1 self) padded to multiple of 8
  if (i < N_BIG) dis[i] = 1.f / sqrtf((float)(deg[N_ATOMS + i] + 1));
}

__global__ __launch_bounds__(256) void scan_phase1(const int* __restrict__ in, int* __restrict__ out,
                                                   int* __restrict__ bsums, int n) {
  __shared__ int lds[256];
  int t = threadIdx.x;
  int base = blockIdx.x * 1024;
  int v[4];
  int s = 0;
#pragma unroll
  for (int j = 0; j < 4; ++j) {
    int i = base + t * 4 + j;
    v[j] = (i < n) ? in[i] : 0;
    s += v[j];
  }
  lds[t] = s;
  __syncthreads();
  for (int off = 1; off < 256; off <<= 1) {
    int x = (t >= off) ? lds[t - off] : 0;
    __syncthreads();
    lds[t] += x;
    __syncthreads();
  }
  int excl = lds[t] - s;
  if (t == 255) bsums[blockIdx.x] = lds[255];
  int run = excl;
#pragma unroll
  for (int j = 0; j < 4; ++j) {
    int i = base + t * 4 + j;
    if (i < n) out[i] = run;
    run += v[j];
  }
}

__global__ __launch_bounds__(256) void scan_phase2(int* __restrict__ bsums, int* __restrict__ total_out, int nb) {
  __shared__ int lds[256];
  int t = threadIdx.x;
  int s = (t < nb) ? bsums[t] : 0;
  lds[t] = s;
  __syncthreads();
  for (int off = 1; off < 256; off <<= 1) {
    int x = (t >= off) ? lds[t - off] : 0;
    __syncthreads();
    lds[t] += x;
    __syncthreads();
  }
  if (t < nb) bsums[t] = lds[t] - s;
  if (t == 255) total_out[0] = lds[255];
}

__global__ void scan_phase3(int* __restrict__ out, const int* __restrict__ bsums, int n) {
  int i = blockIdx.x * 256 + threadIdx.x;
  if (i < n) out[i] += bsums[i >> 10];
}

// ---------------- prep: W -> swizzled fp16 (transposed) + inv pool-norms ----------------
__global__ __launch_bounds__(256) void prep_kernel(const float* __restrict__ W0, const float* __restrict__ W1,
                                                   const float* __restrict__ W2, const float* __restrict__ W3,
                                                   const float* __restrict__ W4, unsigned short* __restrict__ Wsplit,
                                                   const float* __restrict__ p0, const float* __restrict__ p1,
                                                   const float* __restrict__ p2, float* __restrict__ pn) {
  int b = blockIdx.x;
  if (b < 5) {
    const float* W = (b == 0) ? W0 : (b == 1) ? W1 : (b == 2) ? W2 : (b == 3) ? W3 : W4;
    unsigned short* dstH = Wsplit + (size_t)b * 16384;
    int t = threadIdx.x;
    int col = t & 127;
    int half = t >> 7;
#pragma unroll
    for (int kg = 0; kg < 8; ++kg) {
      int k0 = kg * 16 + half * 8;
      f16x8 vh;
#pragma unroll
      for (int j = 0; j < 8; ++j) vh[j] = (_Float16)W[(k0 + j) * 128 + col];
      int byte_off = (col * 256 + k0 * 2) ^ ((col & 7) << 4);
      *(f16x8*)((char*)dstH + byte_off) = vh;
    }
  } else {
    int t = threadIdx.x;
    int g = t >> 6, lane = t & 63;
    if (g < 3) {
      const float* p = (g == 0) ? p0 : (g == 1) ? p1 : p2;
      float2 v = ((const float2*)p)[lane];
      float s = v.x * v.x + v.y * v.y;
#pragma unroll
      for (int off = 32; off; off >>= 1) s += __shfl_xor(s, off);
      if (lane == 0) pn[g] = 1.f / sqrtf(s);
    }
  }
}

// ---------------- MFMA GEMM: H[M,128] = A[M,128](fp16) @ W(fp16, swizzled, L2-hot) -------
// No LDS, no barrier: B-fragments loaded straight from global Wsp (L2-resident, broadcast).
// 4 waves x 32 rows = 128 rows/block; A fragments prefetched.
// If ids != nullptr, A-rows are gathered from the fp32 table embA[ids[row]].
__global__ __launch_bounds__(256) void gemm_f16(const unsigned short* __restrict__ A,
                                                const float* __restrict__ embA, const int* __restrict__ ids,
                                                const unsigned short* __restrict__ Wsp,
                                                unsigned short* __restrict__ H, float* __restrict__ hs,
                                                float* __restrict__ hd, const float* __restrict__ aS,
                                                const float* __restrict__ aD, int M) {
  int t = threadIdx.x;
  int wave = t >> 6, lane = t & 63;
  int lr = lane & 15, lq = lane >> 4;
  int row0 = blockIdx.x * 128 + wave * 32;
  // prefetch all A fragments [ks][rt] — 8 (or 16) independent loads in flight
  f16x8 Af[4][2];
  if (ids) {
    int rid[2];
#pragma unroll
    for (int rt = 0; rt < 2; ++rt) {
      int row = row0 + rt * 16 + lr;
      rid[rt] = (row < M) ? ids[row] : 0;
    }
#pragma unroll
    for (int ks = 0; ks < 4; ++ks)
#pragma unroll
      for (int rt = 0; rt < 2; ++rt) {
        int row = row0 + rt * 16 + lr;
        if (row < M) {
          const float* src = embA + (size_t)rid[rt] * D + ks * 32 + lq * 8;
          float4 v0 = *(const float4*)src;
          float4 v1 = *(const float4*)(src + 4);
          f16x8 a;
          a[0] = (_Float16)v0.x; a[1] = (_Float16)v0.y; a[2] = (_Float16)v0.z; a[3] = (_Float16)v0.w;
          a[4] = (_Float16)v1.x; a[5] = (_Float16)v1.y; a[6] = (_Float16)v1.z; a[7] = (_Float16)v1.w;
          Af[ks][rt] = a;
        } else {
          Af[ks][rt] = (f16x8){0, 0, 0, 0, 0, 0, 0, 0};
        }
      }
  } else {
#pragma unroll
    for (int ks = 0; ks < 4; ++ks)
#pragma unroll
      for (int rt = 0; rt < 2; ++rt) {
        int row = row0 + rt * 16 + lr;
        if (row < M) {
          Af[ks][rt] = *(const f16x8*)(A + (size_t)row * D + ks * 32 + lq * 8);
        } else {
          Af[ks][rt] = (f16x8){0, 0, 0, 0, 0, 0, 0, 0};
        }
      }
  }
  f32x4 acc[2][8];
#pragma unroll
  for (int rt = 0; rt < 2; ++rt)
#pragma unroll
    for (int ct = 0; ct < 8; ++ct) acc[rt][ct] = (f32x4){0.f, 0.f, 0.f, 0.f};

#pragma unroll
  for (int ks = 0; ks < 4; ++ks) {
    int k8 = ks * 32 + lq * 8;
    f16x8 Bh[8];
#pragma unroll
    for (int ct = 0; ct < 8; ++ct) {
      int col = ct * 16 + lr;
      int byte_off = (col * 256 + k8 * 2) ^ ((col & 7) << 4);
      Bh[ct] = *(const f16x8*)((const char*)Wsp + byte_off);
    }
#pragma unroll
    for (int ct = 0; ct < 8; ++ct)
#pragma unroll
      for (int rt = 0; rt < 2; ++rt)
        acc[rt][ct] = __builtin_amdgcn_mfma_f32_16x16x32_f16(Af[ks][rt], Bh[ct], acc[rt][ct], 0, 0, 0);
  }
  // C/D layout: col = lane&15, row = (lane>>4)*4 + i
#pragma unroll
  for (int rt = 0; rt < 2; ++rt)
#pragma unroll
    for (int ct = 0; ct < 8; ++ct) {
      int col = ct * 16 + lr;
#pragma unroll
      for (int i = 0; i < 4; ++i) {
        int row = row0 + rt * 16 + lq * 4 + i;
        if (row < M) {
          _Float16 hv = (_Float16)acc[rt][ct][i];
          H[(size_t)row * D + col] = __builtin_bit_cast(unsigned short, hv);
        }
      }
    }
  if (aS) {
    float sA[8], sD[8];
#pragma unroll
    for (int ct = 0; ct < 8; ++ct) {
      sA[ct] = aS[ct * 16 + lr];
      sD[ct] = aD[ct * 16 + lr];
    }
#pragma unroll
    for (int rt = 0; rt < 2; ++rt)
#pragma unroll
      for (int i = 0; i < 4; ++i) {
        float ps = 0.f, pd = 0.f;
#pragma unroll
        for (int ct = 0; ct < 8; ++ct) {
          ps = fmaf(acc[rt][ct][i], sA[ct], ps);
          pd = fmaf(acc[rt][ct][i], sD[ct], pd);
        }
#pragma unroll
        for (int off = 1; off < 16; off <<= 1) {
          ps += __shfl_xor(ps, off);
          pd += __shfl_xor(pd, off);
        }
        int row = row0 + rt * 16 + lq * 4 + i;
        if (lr == 0 && row < M) {
          hs[row] = ps;
          hd[row] = pd;
        }
      }
  }
}

// ---------------- GAT edge weights: single-pass + L1-hot normalize (pads = 0) ------------
// Writes NORMALIZED weights (w/z) as packed {w,w} fp16.
__global__ void edge_weights(const float* __restrict__ hs, const float* __restrict__ hd,
                             const int* __restrict__ rpx, const int* __restrict__ deg,
                             const int* __restrict__ csx, unsigned* __restrict__ wts, int N) {
  int d = blockIdx.x * 256 + threadIdx.x;
  if (d >= N) return;
  int b = rpx[d];
  int cnt = rpx[d + 1] - b;
  int dg = deg[d];
  float hdd = hd[d];
  float* wf = (float*)wts;
  float z = 0.f;
  for (int j = 0; j < dg; ++j) {
    float w = __expf(leaky(hs[csx[b + j]] + hdd));
    z += w;
    wf[b + j] = w;
  }
  float wself = __expf(leaky(hs[d] + hdd));
  wf[b + dg] = wself;
  z += wself;
  float iz = 1.f / z;
  for (int j = 0; j <= dg; ++j) {
    float wn = wf[b + j] * iz;
    wts[b + j] = packh2(wn, wn);
  }
  for (int j = dg + 1; j < cnt; ++j) wts[b + j] = 0;
}

// ---------------- GCN edge weights (feature-independent, built once; pads = 0) ------------
__global__ void gcn_weights(const int* __restrict__ rpx, const int* __restrict__ deg,
                            const int* __restrict__ csx, const float* __restrict__ dis,
                            unsigned* __restrict__ wtsG, int N) {
  int dl = blockIdx.x * 256 + threadIdx.x;
  if (dl >= N) return;
  int d = N_ATOMS + dl;
  int b = rpx[d];
  int cnt = rpx[d + 1] - b;
  int dg = deg[d];
  float dd = dis[dl];
  for (int j = 0; j < dg; ++j) {
    float w = dis[csx[b + j]] * dd;
    wtsG[b + j] = packh2(w, w);
  }
  wtsG[b + dg] = packh2(dd * dd, dd * dd);
  for (int j = dg + 1; j < cnt; ++j) wtsG[b + j] = 0;
}

// ---------------- GAT gather: 2 dsts per wave (32 lanes each), 16 rows in flight ----------
__global__ __launch_bounds__(256) void gat_gather(const unsigned short* __restrict__ H,
                                                  const int* __restrict__ rpx, const int* __restrict__ csx,
                                                  const unsigned* __restrict__ wts,
                                                  const float* __restrict__ bias,
                                                  const float* __restrict__ poolP, const float* __restrict__ pnL,
                                                  unsigned short* __restrict__ Xout, int N) {
  int wid = (blockIdx.x * 256 + threadIdx.x) >> 6;
  int d0 = __builtin_amdgcn_readfirstlane(wid << 1);
  if (d0 >= N) return;
  int lane = threadIdx.x & 63;
  int half = lane >> 5;
  int hl = lane & 31;
  int rb0 = rpx[d0];
  int rb1 = rpx[d0 + 1];
  int rb2 = rpx[d0 + 2];
  int cnt0 = rb1 - rb0;          // multiples of 8
  int cnt1 = rb2 - rb1;
  int cnt_h = half ? cnt1 : cnt0;
  const uint2* H2 = (const uint2*)H;  // 32 uint2 per row (4 channels per lane)
  float a0 = 0.f, a1 = 0.f, a2 = 0.f, a3 = 0.f;
  for (int i = 0; i < cnt_h; i += 8) {
    int ib = __builtin_amdgcn_readfirstlane(i);
    // scalar streams for both halves (uniform addresses)
    int sA[8], sB[8];
    unsigned wA[8], wB[8];
#pragma unroll
    for (int j = 0; j < 8; ++j) {
      sA[j] = csx[rb0 + ib + j];
      sB[j] = csx[rb1 + ib + j];
      wA[j] = wts[rb0 + ib + j];
      wB[j] = wts[rb1 + ib + j];
    }
    h2_t acc0 = (h2_t){(_Float16)0.f, (_Float16)0.f};
    h2_t acc1 = acc0;
#pragma unroll
    for (int j = 0; j < 8; ++j) {
      int sj = half ? sB[j] : sA[j];
      unsigned wj = half ? wB[j] : wA[j];
      uint2 hv = H2[(size_t)sj * 32 + hl];
      h2_t wh = u2h(wj);
      acc0 += wh * u2h(hv.x);
      acc1 += wh * u2h(hv.y);
    }
    a0 += (float)acc0[0];
    a1 += (float)acc0[1];
    a2 += (float)acc1[0];
    a3 += (float)acc1[1];
  }
  float4 b4 = ((const float4*)bias)[hl];
  a0 = fmaxf(a0 + b4.x, 0.f);
  a1 = fmaxf(a1 + b4.y, 0.f);
  a2 = fmaxf(a2 + b4.z, 0.f);
  a3 = fmaxf(a3 + b4.w, 0.f);
  float4 p4 = ((const float4*)poolP)[hl];
  float dot = a0 * p4.x + a1 * p4.y + a2 * p4.z + a3 * p4.w;
#pragma unroll
  for (int off = 16; off; off >>= 1) dot += __shfl_xor(dot, off);  // within each half
  float sc = fast_tanh(dot * pnL[0]);
  uint2 o;
  o.x = packh2(a0 * sc, a1 * sc);
  o.y = packh2(a2 * sc, a3 * sc);
  ((uint2*)Xout)[(size_t)(d0 + half) * 32 + hl] = o;
}

// ---------------- GCN gather: 8 rows in flight; fp16 or fp32 out ----------------
__global__ __launch_bounds__(256) void gcn_gather(const unsigned short* __restrict__ Y,
                                                  const int* __restrict__ rpx, const int* __restrict__ csx,
                                                  const unsigned* __restrict__ wtsG, const float* __restrict__ b,
                                                  unsigned short* __restrict__ outB, float* __restrict__ outF,
                                                  int N) {
  int wid = (blockIdx.x * 256 + threadIdx.x) >> 6;
  int dl = __builtin_amdgcn_readfirstlane(wid);
  if (dl >= N) return;
  int lane = threadIdx.x & 63;
  int rb = rpx[N_ATOMS + dl];
  int cnt = rpx[N_ATOMS + dl + 1] - rb;
  const unsigned* Y2 = (const unsigned*)Y;
  float ax = 0.f, ay = 0.f;
  for (int i = 0; i < cnt; i += 8) {
    int s0 = csx[rb + i + 0], s1 = csx[rb + i + 1], s2 = csx[rb + i + 2], s3 = csx[rb + i + 3];
    int s4 = csx[rb + i + 4], s5 = csx[rb + i + 5], s6 = csx[rb + i + 6], s7 = csx[rb + i + 7];
    unsigned w0 = wtsG[rb + i + 0], w1 = wtsG[rb + i + 1], w2 = wtsG[rb + i + 2], w3 = wtsG[rb + i + 3];
    unsigned w4 = wtsG[rb + i + 4], w5 = wtsG[rb + i + 5], w6 = wtsG[rb + i + 6], w7 = wtsG[rb + i + 7];
    unsigned h0 = Y2[(size_t)s0 * 64 + lane];
    unsigned h1 = Y2[(size_t)s1 * 64 + lane];
    unsigned h2 = Y2[(size_t)s2 * 64 + lane];
    unsigned h3 = Y2[(size_t)s3 * 64 + lane];
    unsigned h4 = Y2[(size_t)s4 * 64 + lane];
    unsigned h5 = Y2[(size_t)s5 * 64 + lane];
    unsigned h6 = Y2[(size_t)s6 * 64 + lane];
    unsigned h7 = Y2[(size_t)s7 * 64 + lane];
    h2_t a2 = u2h(w0) * u2h(h0);
    a2 += u2h(w1) * u2h(h1);
    a2 += u2h(w2) * u2h(h2);
    a2 += u2h(w3) * u2h(h3);
    h2_t b2h = u2h(w4) * u2h(h4);
    b2h += u2h(w5) * u2h(h5);
    b2h += u2h(w6) * u2h(h6);
    b2h += u2h(w7) * u2h(h7);
    a2 += b2h;
    ax += (float)a2[0];
    ay += (float)a2[1];
  }
  float2 b2 = ((const float2*)b)[lane];
  float ox = fmaxf(ax + b2.x, 0.f);
  float oy = fmaxf(ay + b2.y, 0.f);
  if (outF)
    ((float2*)outF)[(size_t)dl * 64 + lane] = make_float2(ox, oy);
  else
    ((unsigned*)outB)[(size_t)dl * 64 + lane] = packh2(ox, oy);
}

__global__ void group_bounds(const int* __restrict__ batch, int* __restrict__ gs, int* __restrict__ ge, int n) {
  int i = blockIdx.x * 256 + threadIdx.x;
  if (i >= n) return;
  int b = batch[i];
  if (i == 0 || batch[i - 1] != b) gs[b] = i;
  if (i == n - 1 || batch[i + 1] != b) ge[b] = i + 1;
}

// per-group max & mean; 4 waves split rows, LDS combine
__global__ __launch_bounds__(256) void pool_kernel(const unsigned short* __restrict__ X,
                                                   const int* __restrict__ gs, const int* __restrict__ ge,
                                                   float* __restrict__ x123) {
  __shared__ float2 mxs[4][64];
  __shared__ float2 sms[4][64];
  int g = blockIdx.x;
  int wv = threadIdx.x >> 6;
  int p = threadIdx.x & 63;
  int beg = gs[g], end = ge[g];
  int cnt = end - beg;
  const unsigned* X2 = (const unsigned*)X;
  float mx0 = -FLT_MAX, mx1 = -FLT_MAX, sm0 = 0.f, sm1 = 0.f;
  for (int i = beg + wv; i < end; i += 4) {
    h2_t v = u2h(X2[(size_t)i * 64 + p]);
    float a = (float)v[0], b = (float)v[1];
    mx0 = fmaxf(mx0, a);
    mx1 = fmaxf(mx1, b);
    sm0 += a;
    sm1 += b;
  }
  mxs[wv][p] = make_float2(mx0, mx1);
  sms[wv][p] = make_float2(sm0, sm1);
  __syncthreads();
  if (threadIdx.x < 64 && cnt > 0) {
#pragma unroll
    for (int k = 1; k < 4; ++k) {
      float2 m2 = mxs[k][p], s2 = sms[k][p];
      mx0 = fmaxf(mx0, m2.x);
      mx1 = fmaxf(mx1, m2.y);
      sm0 += s2.x;
      sm1 += s2.y;
    }
    float inv = 1.f / (float)cnt;
    float* xg = x123 + (size_t)g * 256;
    xg[2 * p] += mx0;
    xg[2 * p + 1] += mx1;
    xg[128 + 2 * p] += sm0 * inv;
    xg[128 + 2 * p + 1] += sm1 * inv;
  }
}

// xDP = relu(x123 @ lin1_W + lin1_b), fp16 out
__global__ __launch_bounds__(128) void lin1_kernel(const float* __restrict__ x123, const float* __restrict__ W,
                                                   const float* __restrict__ b, unsigned short* __restrict__ xb) {
  __shared__ float row[256];
  int g = blockIdx.x;
  int c = threadIdx.x;
  row[c] = x123[(size_t)g * 256 + c];
  row[c + 128] = x123[(size_t)g * 256 + 128 + c];
  __syncthreads();
  float acc = b[c];
#pragma unroll 8
  for (int k = 0; k < 256; ++k) acc = fmaf(row[k], W[k * 128 + c], acc);
  _Float16 hv = (_Float16)fmaxf(acc, 0.f);
  xb[(size_t)g * D + c] = __builtin_bit_cast(unsigned short, hv);
}

__global__ void xse_kernel(const float* __restrict__ emb, const int* __restrict__ x_ids,
                           const int* __restrict__ nDrugPtr, int nProtein, unsigned short* __restrict__ xb) {
  int idx = blockIdx.x * 256 + threadIdx.x;
  int r = idx >> 6, lane = idx & 63;
  int off = nDrugPtr[0] + nProtein;
  int id = x_ids[off + r];
  float2 v = ((const float2*)(emb + (size_t)id * D))[lane];
  ((unsigned*)xb)[(size_t)(G_GROUPS + r) * 64 + lane] = packh2(v.x, v.y);
}

__global__ void out_gather(const float* __restrict__ xb, const int* __restrict__ dn, const int* __restrict__ sn,
                           float* __restrict__ out) {
  int idx = blockIdx.x * 256 + threadIdx.x;
  int r = idx >> 6, lane = idx & 63;
  int s = (r < 1000) ? dn[r] : (r < 6000) ? sn[r - 1000] : (r - 6000);
  ((float2*)out)[(size_t)idx] = ((const float2*)(xb + (size_t)s * D))[lane];
}

extern "C" void kernel_launch(void* const* d_in, const int* in_sizes, int n_in, void* d_out, int out_size,
                              void* d_ws, size_t ws_size, hipStream_t stream) {
  const int* x_ids = (const int*)d_in[0];
  const int* drugE = (const int*)d_in[1];
  const int* drugNodes = (const int*)d_in[3];
  const int* seNodes = (const int*)d_in[4];
  int nProtein = in_sizes[5];
  const int* atom_x = (const int*)d_in[7];
  const int* atomE = (const int*)d_in[8];
  const int* atom_batch = (const int*)d_in[9];
  const int* nDrugPtr = (const int*)d_in[10];
  const float* emb = (const float*)d_in[11];
  const float* gatW[3] = {(const float*)d_in[12], (const float*)d_in[17], (const float*)d_in[22]};
  const float* attS[3] = {(const float*)d_in[13], (const float*)d_in[18], (const float*)d_in[23]};
  const float* attD[3] = {(const float*)d_in[14], (const float*)d_in[19], (const float*)d_in[24]};
  const float* gatB[3] = {(const float*)d_in[15], (const float*)d_in[20], (const float*)d_in[25]};
  const float* poolP[3] = {(const float*)d_in[16], (const float*)d_in[21], (const float*)d_in[26]};
  const float* lin1_W = (const float*)d_in[27];
  const float* lin1_b = (const float*)d_in[28];
  const float* gcn1_W = (const float*)d_in[29];
  const float* gcn1_b = (const float*)d_in[30];
  const float* gcn2_W = (const float*)d_in[31];
  const float* gcn2_b = (const float*)d_in[32];
  float* out = (float*)d_out;
  (void)n_in; (void)out_size; (void)ws_size;

  const int MAXX = E_ALL + 8 * N_ALL + 64;  // padded entry upper bound (+slack for scalar over-read)

  char* ws = (char*)d_ws;
  size_t off = 0;
  auto alloc = [&](size_t bytes) -> char* {
    char* p = ws + off;
    off += (bytes + 255) & ~(size_t)255;
    return p;
  };
  unsigned short* bufA = (unsigned short*)alloc((size_t)N_ATOMS * D * 2);  // xa (fp16)
  unsigned short* bufB = (unsigned short*)alloc((size_t)N_ATOMS * D * 2);  // h  (fp16)
  float* hs = (float*)alloc((size_t)N_ATOMS * 4);
  float* hd = (float*)alloc((size_t)N_ATOMS * 4);
  int* csx = (int*)alloc((size_t)MAXX * 4);
  unsigned* wts = (unsigned*)alloc((size_t)MAXX * 4);
  unsigned* wtsG = (unsigned*)alloc((size_t)MAXX * 4);
  int* rank = (int*)alloc((size_t)E_ALL * 4);
  float* x123 = (float*)alloc((size_t)G_GROUPS * 256 * 4);
  unsigned short* xb1 = (unsigned short*)alloc((size_t)N_BIG * D * 2);
  unsigned short* xb2 = (unsigned short*)alloc((size_t)N_BIG * D * 2);
  float* xbF = (float*)alloc((size_t)N_BIG * D * 4);
  unsigned short* Wsplit = (unsigned short*)alloc((size_t)5 * 16384 * 2);
  int* rpx = (int*)alloc((size_t)(N_ALL + 2) * 4);
  int* deg = (int*)alloc((size_t)N_ALL * 4);
  int* cntp = (int*)alloc((size_t)N_ALL * 4);
  float* disB = (float*)alloc((size_t)N_BIG * 4);
  int* gs = (int*)alloc((size_t)G_GROUPS * 4);
  int* ge = (int*)alloc((size_t)G_GROUPS * 4);
  int* bsums = (int*)alloc(256 * 4);
  float* pn = (float*)alloc(256);

  const int* asrc = atomE;
  const int* adst = atomE + E_ATOMS;
  const int* dsrc = drugE;
  const int* ddst = drugE + E_BIG;

  // ---- prep (weight fp16 + pool norms) ----
  prep_kernel<<<6, 256, 0, stream>>>(gatW[0], gatW[1], gatW[2], gcn1_W, gcn2_W, Wsplit, poolP[0], poolP[1],
                                     poolP[2], pn);

  // ---- merged CSR (rank-based, padded to multiple of 8) ----
  hipMemsetAsync(deg, 0, (size_t)N_ALL * 4, stream);
  count_all<<<ceil_div(E_ALL, 256), 256, 0, stream>>>(adst, ddst, deg, rank);
  post_count<<<ceil_div(N_ALL, 256), 256, 0, stream>>>(deg, cntp, disB);
  scan_phase1<<<ceil_div(N_ALL, 1024), 256, 0, stream>>>(cntp, rpx, bsums, N_ALL);
  scan_phase2<<<1, 256, 0, stream>>>(bsums, rpx + N_ALL, ceil_div(N_ALL, 1024));
  scan_phase3<<<ceil_div(N_ALL, 256), 256, 0, stream>>>(rpx, bsums, N_ALL);
  fill_csx<<<ceil_div(E_ALL, 256), 256, 0, stream>>>(asrc, adst, dsrc, ddst, rpx, rank, csx);
  fill_pad<<<ceil_div(N_ALL, 256), 256, 0, stream>>>(deg, rpx, csx);
  gcn_weights<<<ceil_div(N_BIG, 256), 256, 0, stream>>>(rpx, deg, csx, disB, wtsG, N_BIG);

  // ---- group ranges ----
  hipMemsetAsync(gs, 0, (size_t)G_GROUPS * 4, stream);
  hipMemsetAsync(ge, 0, (size_t)G_GROUPS * 4, stream);
  group_bounds<<<ceil_div(N_ATOMS, 256), 256, 0, stream>>>(atom_batch, gs, ge, N_ATOMS);

  hipMemsetAsync(x123, 0, (size_t)G_GROUPS * 256 * 4, stream);

  // ---- 3 GAT layers (layer 0 gathers A-rows directly from the fp32 emb table) ----
  for (int L = 0; L < 3; ++L) {
    gemm_f16<<<ceil_div(N_ATOMS, 128), 256, 0, stream>>>(bufA, emb, (L == 0) ? atom_x : nullptr,
                                                         Wsplit + (size_t)L * 16384, bufB, hs, hd, attS[L],
                                                         attD[L], N_ATOMS);
    edge_weights<<<ceil_div(N_ATOMS, 256), 256, 0, stream>>>(hs, hd, rpx, deg, csx, wts, N_ATOMS);
    gat_gather<<<ceil_div(N_ATOMS / 2 * 64, 256), 256, 0, stream>>>(bufB, rpx, csx, wts, gatB[L], poolP[L],
                                                                    pn + L, bufA, N_ATOMS);
    pool_kernel<<<G_GROUPS, 256, 0, stream>>>(bufA, gs, ge, x123);
  }

  // ---- MLP + big-graph node features ----
  lin1_kernel<<<G_GROUPS, 128, 0, stream>>>(x123, lin1_W, lin1_b, xb1);
  xse_kernel<<<(N_BIG - G_GROUPS) * 64 / 256, 256, 0, stream>>>(emb, x_ids, nDrugPtr, nProtein, xb1);

  // ---- 2 GCN layers ----
  gemm_f16<<<ceil_div(N_BIG, 128), 256, 0, stream>>>(xb1, nullptr, nullptr, Wsplit + (size_t)3 * 16384, bufB,
                                                     nullptr, nullptr, nullptr, nullptr, N_BIG);
  gcn_gather<<<N_BIG * 64 / 256, 256, 0, stream>>>(bufB, rpx, csx, wtsG, gcn1_b, xb2, nullptr, N_BIG);
  gemm_f16<<<ceil_div(N_BIG, 128), 256, 0, stream>>>(xb2, nullptr, nullptr, Wsplit + (size_t)4 * 16384, bufB,
                                                     nullptr, nullptr, nullptr, nullptr, N_BIG);
  gcn_gather<<<N_BIG * 64 / 256, 256, 0, stream>>>(bufB, rpx, csx, wtsG, gcn2_b, nullptr, xbF, N_BIG);

  // ---- outputs ----
  out_gather<<<13000 * 64 / 256, 256, 0, stream>>>(xbF, drugNodes, seNodes, out);
}

// Round 19
// 497.097 us; speedup vs baseline: 1.0489x; 1.0489x over previous
//
#include <hip/hip_runtime.h>
#include <cfloat>
#include <cmath>

#define D 128
#define N_ATOMS 200000
#define E_ATOMS 800000
#define G_GROUPS 2000
#define N_BIG 7000
#define E_BIG 200000
#define N_ALL (N_ATOMS + N_BIG)
#define E_ALL (E_ATOMS + E_BIG)

static inline int ceil_div(int a, int b) { return (a + b - 1) / b; }

typedef __attribute__((ext_vector_type(8))) _Float16 f16x8;
typedef __attribute__((ext_vector_type(2))) _Float16 h2_t;
typedef __attribute__((ext_vector_type(4))) float f32x4;

__device__ inline h2_t u2h(unsigned u) { return __builtin_bit_cast(h2_t, u); }
__device__ inline unsigned h2u(h2_t h) { return __builtin_bit_cast(unsigned, h); }
__device__ inline unsigned packh2(float x, float y) {
  h2_t h;
  h[0] = (_Float16)x;
  h[1] = (_Float16)y;
  return h2u(h);
}
__device__ inline float leaky(float e) { return fmaxf(e, 0.2f * e); }
__device__ inline float fast_tanh(float x) {
  float cx = fminf(fmaxf(x, -15.f), 15.f);
  float t = __expf(2.f * cx);
  return (t - 1.f) * __frcp_rn(t + 1.f);
}

// ---------------- CSR build (both graphs merged, rank-based, atomic only in count) --------
__global__ void count_all(const int* __restrict__ adst, const int* __restrict__ ddst, int* __restrict__ deg,
                          int* __restrict__ rank) {
  int i = blockIdx.x * 256 + threadIdx.x;
  if (i < E_ATOMS)
    rank[i] = atomicAdd(&deg[adst[i]], 1);
  else if (i < E_ALL)
    rank[i] = atomicAdd(&deg[N_ATOMS + ddst[i - E_ATOMS]], 1);
}

__global__ void fill_csx(const int* __restrict__ asrc, const int* __restrict__ adst,
                         const int* __restrict__ dsrc, const int* __restrict__ ddst,
                         const int* __restrict__ rpx, const int* __restrict__ rank, int* __restrict__ csx) {
  int i = blockIdx.x * 256 + threadIdx.x;
  if (i < E_ATOMS) {
    csx[rpx[adst[i]] + rank[i]] = asrc[i];
  } else if (i < E_ALL) {
    int k = i - E_ATOMS;
    csx[rpx[N_ATOMS + ddst[k]] + rank[i]] = dsrc[k];
  }
}

// self entry + pad entries (src = self) for every node
__global__ void fill_pad(const int* __restrict__ deg, const int* __restrict__ rpx, int* __restrict__ csx) {
  int d = blockIdx.x * 256 + threadIdx.x;
  if (d >= N_ALL) return;
  int dg = deg[d];
  int b = rpx[d], e = rpx[d + 1];
  int sv = (d < N_ATOMS) ? d : d - N_ATOMS;  // big-graph srcs are local indices
  for (int j = b + dg; j < e; ++j) csx[j] = sv;
}

// cntp for all nodes + dis for big-graph nodes (merged)
__global__ void post_count(const int* __restrict__ deg, int* __restrict__ cntp, float* __restrict__ dis) {
  int i = blockIdx.x * 256 + threadIdx.x;
  if (i < N_ALL) cntp[i] = (deg[i] + 8) & ~7;  // (deg + 1 self) padded to multiple of 8
  if (i < N_BIG) dis[i] = 1.f / sqrtf((float)(deg[N_ATOMS + i] + 1));
}

__global__ __launch_bounds__(256) void scan_phase1(const int* __restrict__ in, int* __restrict__ out,
                                                   int* __restrict__ bsums, int n) {
  __shared__ int lds[256];
  int t = threadIdx.x;
  int base = blockIdx.x * 1024;
  int v[4];
  int s = 0;
#pragma unroll
  for (int j = 0; j < 4; ++j) {
    int i = base + t * 4 + j;
    v[j] = (i < n) ? in[i] : 0;
    s += v[j];
  }
  lds[t] = s;
  __syncthreads();
  for (int off = 1; off < 256; off <<= 1) {
    int x = (t >= off) ? lds[t - off] : 0;
    __syncthreads();
    lds[t] += x;
    __syncthreads();
  }
  int excl = lds[t] - s;
  if (t == 255) bsums[blockIdx.x] = lds[255];
  int run = excl;
#pragma unroll
  for (int j = 0; j < 4; ++j) {
    int i = base + t * 4 + j;
    if (i < n) out[i] = run;
    run += v[j];
  }
}

__global__ __launch_bounds__(256) void scan_phase2(int* __restrict__ bsums, int* __restrict__ total_out, int nb) {
  __shared__ int lds[256];
  int t = threadIdx.x;
  int s = (t < nb) ? bsums[t] : 0;
  lds[t] = s;
  __syncthreads();
  for (int off = 1; off < 256; off <<= 1) {
    int x = (t >= off) ? lds[t - off] : 0;
    __syncthreads();
    lds[t] += x;
    __syncthreads();
  }
  if (t < nb) bsums[t] = lds[t] - s;
  if (t == 255) total_out[0] = lds[255];
}

__global__ void scan_phase3(int* __restrict__ out, const int* __restrict__ bsums, int n) {
  int i = blockIdx.x * 256 + threadIdx.x;
  if (i < n) out[i] += bsums[i >> 10];
}

// ---------------- prep: W -> swizzled fp16 (transposed) + inv pool-norms ----------------
__global__ __launch_bounds__(256) void prep_kernel(const float* __restrict__ W0, const float* __restrict__ W1,
                                                   const float* __restrict__ W2, const float* __restrict__ W3,
                                                   const float* __restrict__ W4, unsigned short* __restrict__ Wsplit,
                                                   const float* __restrict__ p0, const float* __restrict__ p1,
                                                   const float* __restrict__ p2, float* __restrict__ pn) {
  int b = blockIdx.x;
  if (b < 5) {
    const float* W = (b == 0) ? W0 : (b == 1) ? W1 : (b == 2) ? W2 : (b == 3) ? W3 : W4;
    unsigned short* dstH = Wsplit + (size_t)b * 16384;
    int t = threadIdx.x;
    int col = t & 127;
    int half = t >> 7;
#pragma unroll
    for (int kg = 0; kg < 8; ++kg) {
      int k0 = kg * 16 + half * 8;
      f16x8 vh;
#pragma unroll
      for (int j = 0; j < 8; ++j) vh[j] = (_Float16)W[(k0 + j) * 128 + col];
      int byte_off = (col * 256 + k0 * 2) ^ ((col & 7) << 4);
      *(f16x8*)((char*)dstH + byte_off) = vh;
    }
  } else {
    int t = threadIdx.x;
    int g = t >> 6, lane = t & 63;
    if (g < 3) {
      const float* p = (g == 0) ? p0 : (g == 1) ? p1 : p2;
      float2 v = ((const float2*)p)[lane];
      float s = v.x * v.x + v.y * v.y;
#pragma unroll
      for (int off = 32; off; off >>= 1) s += __shfl_xor(s, off);
      if (lane == 0) pn[g] = 1.f / sqrtf(s);
    }
  }
}

// ---------------- MFMA GEMM: H[M,128] = A[M,128](fp16) @ W(fp16, swizzled) ----------
// 4 waves x 32 rows; each block processes 2 tiles (256 rows) off one W staging.
// Tile-1 A loads are issued before tile-0 compute -> hidden under MFMA.
// If ids != nullptr, A-rows are gathered from the fp32 table embA[ids[row]].
__global__ __launch_bounds__(256) void gemm_f16(const unsigned short* __restrict__ A,
                                                const float* __restrict__ embA, const int* __restrict__ ids,
                                                const unsigned short* __restrict__ Wsp,
                                                unsigned short* __restrict__ H, float* __restrict__ hs,
                                                float* __restrict__ hd, const float* __restrict__ aS,
                                                const float* __restrict__ aD, int M) {
  __shared__ unsigned short Wl[16384];  // transposed [col][k], XOR-swizzled (32 KB)
  int t = threadIdx.x;
  {
    const uint4* src = (const uint4*)Wsp;
    uint4* dst = (uint4*)Wl;
#pragma unroll
    for (int i = 0; i < 8; ++i) dst[t + i * 256] = src[t + i * 256];
  }
  int wave = t >> 6, lane = t & 63;
  int lr = lane & 15, lq = lane >> 4;
  int base0 = blockIdx.x * 256 + wave * 32;
  int base1 = base0 + 128;

  auto loadA = [&](f16x8 (&Af)[4][2], int row0) {
    if (ids) {
      int rid[2];
#pragma unroll
      for (int rt = 0; rt < 2; ++rt) {
        int row = row0 + rt * 16 + lr;
        rid[rt] = (row < M) ? ids[row] : 0;
      }
#pragma unroll
      for (int ks = 0; ks < 4; ++ks)
#pragma unroll
        for (int rt = 0; rt < 2; ++rt) {
          int row = row0 + rt * 16 + lr;
          if (row < M) {
            const float* src = embA + (size_t)rid[rt] * D + ks * 32 + lq * 8;
            float4 v0 = *(const float4*)src;
            float4 v1 = *(const float4*)(src + 4);
            f16x8 a;
            a[0] = (_Float16)v0.x; a[1] = (_Float16)v0.y; a[2] = (_Float16)v0.z; a[3] = (_Float16)v0.w;
            a[4] = (_Float16)v1.x; a[5] = (_Float16)v1.y; a[6] = (_Float16)v1.z; a[7] = (_Float16)v1.w;
            Af[ks][rt] = a;
          } else {
            Af[ks][rt] = (f16x8){0, 0, 0, 0, 0, 0, 0, 0};
          }
        }
    } else {
#pragma unroll
      for (int ks = 0; ks < 4; ++ks)
#pragma unroll
        for (int rt = 0; rt < 2; ++rt) {
          int row = row0 + rt * 16 + lr;
          if (row < M) {
            Af[ks][rt] = *(const f16x8*)(A + (size_t)row * D + ks * 32 + lq * 8);
          } else {
            Af[ks][rt] = (f16x8){0, 0, 0, 0, 0, 0, 0, 0};
          }
        }
    }
  };

  auto computeStore = [&](f16x8 (&Af)[4][2], int row0) {
    f32x4 acc[2][8];
#pragma unroll
    for (int rt = 0; rt < 2; ++rt)
#pragma unroll
      for (int ct = 0; ct < 8; ++ct) acc[rt][ct] = (f32x4){0.f, 0.f, 0.f, 0.f};
#pragma unroll
    for (int ks = 0; ks < 4; ++ks) {
      int k8 = ks * 32 + lq * 8;
#pragma unroll
      for (int ct = 0; ct < 8; ++ct) {
        int col = ct * 16 + lr;
        int byte_off = (col * 256 + k8 * 2) ^ ((col & 7) << 4);
        f16x8 Bh = *(f16x8*)((char*)Wl + byte_off);
#pragma unroll
        for (int rt = 0; rt < 2; ++rt)
          acc[rt][ct] = __builtin_amdgcn_mfma_f32_16x16x32_f16(Af[ks][rt], Bh, acc[rt][ct], 0, 0, 0);
      }
    }
    // C/D layout: col = lane&15, row = (lane>>4)*4 + i
#pragma unroll
    for (int rt = 0; rt < 2; ++rt)
#pragma unroll
      for (int ct = 0; ct < 8; ++ct) {
        int col = ct * 16 + lr;
#pragma unroll
        for (int i = 0; i < 4; ++i) {
          int row = row0 + rt * 16 + lq * 4 + i;
          if (row < M) {
            _Float16 hv = (_Float16)acc[rt][ct][i];
            H[(size_t)row * D + col] = __builtin_bit_cast(unsigned short, hv);
          }
        }
      }
    if (aS) {
      float sA[8], sD[8];
#pragma unroll
      for (int ct = 0; ct < 8; ++ct) {
        sA[ct] = aS[ct * 16 + lr];
        sD[ct] = aD[ct * 16 + lr];
      }
#pragma unroll
      for (int rt = 0; rt < 2; ++rt)
#pragma unroll
        for (int i = 0; i < 4; ++i) {
          float ps = 0.f, pd = 0.f;
#pragma unroll
          for (int ct = 0; ct < 8; ++ct) {
            ps = fmaf(acc[rt][ct][i], sA[ct], ps);
            pd = fmaf(acc[rt][ct][i], sD[ct], pd);
          }
#pragma unroll
          for (int off = 1; off < 16; off <<= 1) {
            ps += __shfl_xor(ps, off);
            pd += __shfl_xor(pd, off);
          }
          int row = row0 + rt * 16 + lq * 4 + i;
          if (lr == 0 && row < M) {
            hs[row] = ps;
            hd[row] = pd;
          }
        }
    }
  };

  f16x8 A0[4][2], A1[4][2];
  loadA(A0, base0);
  __syncthreads();
  loadA(A1, base1);       // in flight during tile-0 compute
  computeStore(A0, base0);
  computeStore(A1, base1);
}

// ---------------- GAT edge weights: single-pass + L1-hot normalize (pads = 0) ------------
// Writes NORMALIZED weights (w/z) as packed {w,w} fp16.
__global__ void edge_weights(const float* __restrict__ hs, const float* __restrict__ hd,
                             const int* __restrict__ rpx, const int* __restrict__ deg,
                             const int* __restrict__ csx, unsigned* __restrict__ wts, int N) {
  int d = blockIdx.x * 256 + threadIdx.x;
  if (d >= N) return;
  int b = rpx[d];
  int cnt = rpx[d + 1] - b;
  int dg = deg[d];
  float hdd = hd[d];
  float* wf = (float*)wts;
  float z = 0.f;
  for (int j = 0; j < dg; ++j) {
    float w = __expf(leaky(hs[csx[b + j]] + hdd));
    z += w;
    wf[b + j] = w;
  }
  float wself = __expf(leaky(hs[d] + hdd));
  wf[b + dg] = wself;
  z += wself;
  float iz = 1.f / z;
  for (int j = 0; j <= dg; ++j) {
    float wn = wf[b + j] * iz;
    wts[b + j] = packh2(wn, wn);
  }
  for (int j = dg + 1; j < cnt; ++j) wts[b + j] = 0;
}

// ---------------- GCN edge weights (feature-independent, built once; pads = 0) ------------
__global__ void gcn_weights(const int* __restrict__ rpx, const int* __restrict__ deg,
                            const int* __restrict__ csx, const float* __restrict__ dis,
                            unsigned* __restrict__ wtsG, int N) {
  int dl = blockIdx.x * 256 + threadIdx.x;
  if (dl >= N) return;
  int d = N_ATOMS + dl;
  int b = rpx[d];
  int cnt = rpx[d + 1] - b;
  int dg = deg[d];
  float dd = dis[dl];
  for (int j = 0; j < dg; ++j) {
    float w = dis[csx[b + j]] * dd;
    wtsG[b + j] = packh2(w, w);
  }
  wtsG[b + dg] = packh2(dd * dd, dd * dd);
  for (int j = dg + 1; j < cnt; ++j) wtsG[b + j] = 0;
}

// ---------------- GAT gather: 2 dsts per wave (32 lanes each), 16 rows in flight ----------
__global__ __launch_bounds__(256) void gat_gather(const unsigned short* __restrict__ H,
                                                  const int* __restrict__ rpx, const int* __restrict__ csx,
                                                  const unsigned* __restrict__ wts,
                                                  const float* __restrict__ bias,
                                                  const float* __restrict__ poolP, const float* __restrict__ pnL,
                                                  unsigned short* __restrict__ Xout, int N) {
  int wid = (blockIdx.x * 256 + threadIdx.x) >> 6;
  int d0 = __builtin_amdgcn_readfirstlane(wid << 1);
  if (d0 >= N) return;
  int lane = threadIdx.x & 63;
  int half = lane >> 5;
  int hl = lane & 31;
  int rb0 = rpx[d0];
  int rb1 = rpx[d0 + 1];
  int rb2 = rpx[d0 + 2];
  int cnt0 = rb1 - rb0;          // multiples of 8
  int cnt1 = rb2 - rb1;
  int cnt_h = half ? cnt1 : cnt0;
  const uint2* H2 = (const uint2*)H;  // 32 uint2 per row (4 channels per lane)
  float a0 = 0.f, a1 = 0.f, a2 = 0.f, a3 = 0.f;
  for (int i = 0; i < cnt_h; i += 8) {
    int ib = __builtin_amdgcn_readfirstlane(i);
    // scalar streams for both halves (uniform addresses)
    int sA[8], sB[8];
    unsigned wA[8], wB[8];
#pragma unroll
    for (int j = 0; j < 8; ++j) {
      sA[j] = csx[rb0 + ib + j];
      sB[j] = csx[rb1 + ib + j];
      wA[j] = wts[rb0 + ib + j];
      wB[j] = wts[rb1 + ib + j];
    }
    h2_t acc0 = (h2_t){(_Float16)0.f, (_Float16)0.f};
    h2_t acc1 = acc0;
#pragma unroll
    for (int j = 0; j < 8; ++j) {
      int sj = half ? sB[j] : sA[j];
      unsigned wj = half ? wB[j] : wA[j];
      uint2 hv = H2[(size_t)sj * 32 + hl];
      h2_t wh = u2h(wj);
      acc0 += wh * u2h(hv.x);
      acc1 += wh * u2h(hv.y);
    }
    a0 += (float)acc0[0];
    a1 += (float)acc0[1];
    a2 += (float)acc1[0];
    a3 += (float)acc1[1];
  }
  float4 b4 = ((const float4*)bias)[hl];
  a0 = fmaxf(a0 + b4.x, 0.f);
  a1 = fmaxf(a1 + b4.y, 0.f);
  a2 = fmaxf(a2 + b4.z, 0.f);
  a3 = fmaxf(a3 + b4.w, 0.f);
  float4 p4 = ((const float4*)poolP)[hl];
  float dot = a0 * p4.x + a1 * p4.y + a2 * p4.z + a3 * p4.w;
#pragma unroll
  for (int off = 16; off; off >>= 1) dot += __shfl_xor(dot, off);  // within each half
  float sc = fast_tanh(dot * pnL[0]);
  uint2 o;
  o.x = packh2(a0 * sc, a1 * sc);
  o.y = packh2(a2 * sc, a3 * sc);
  ((uint2*)Xout)[(size_t)(d0 + half) * 32 + hl] = o;
}

// ---------------- GCN gather: 8 rows in flight; fp16 or fp32 out ----------------
__global__ __launch_bounds__(256) void gcn_gather(const unsigned short* __restrict__ Y,
                                                  const int* __restrict__ rpx, const int* __restrict__ csx,
                                                  const unsigned* __restrict__ wtsG, const float* __restrict__ b,
                                                  unsigned short* __restrict__ outB, float* __restrict__ outF,
                                                  int N) {
  int wid = (blockIdx.x * 256 + threadIdx.x) >> 6;
  int dl = __builtin_amdgcn_readfirstlane(wid);
  if (dl >= N) return;
  int lane = threadIdx.x & 63;
  int rb = rpx[N_ATOMS + dl];
  int cnt = rpx[N_ATOMS + dl + 1] - rb;
  const unsigned* Y2 = (const unsigned*)Y;
  float ax = 0.f, ay = 0.f;
  for (int i = 0; i < cnt; i += 8) {
    int s0 = csx[rb + i + 0], s1 = csx[rb + i + 1], s2 = csx[rb + i + 2], s3 = csx[rb + i + 3];
    int s4 = csx[rb + i + 4], s5 = csx[rb + i + 5], s6 = csx[rb + i + 6], s7 = csx[rb + i + 7];
    unsigned w0 = wtsG[rb + i + 0], w1 = wtsG[rb + i + 1], w2 = wtsG[rb + i + 2], w3 = wtsG[rb + i + 3];
    unsigned w4 = wtsG[rb + i + 4], w5 = wtsG[rb + i + 5], w6 = wtsG[rb + i + 6], w7 = wtsG[rb + i + 7];
    unsigned h0 = Y2[(size_t)s0 * 64 + lane];
    unsigned h1 = Y2[(size_t)s1 * 64 + lane];
    unsigned h2 = Y2[(size_t)s2 * 64 + lane];
    unsigned h3 = Y2[(size_t)s3 * 64 + lane];
    unsigned h4 = Y2[(size_t)s4 * 64 + lane];
    unsigned h5 = Y2[(size_t)s5 * 64 + lane];
    unsigned h6 = Y2[(size_t)s6 * 64 + lane];
    unsigned h7 = Y2[(size_t)s7 * 64 + lane];
    h2_t a2 = u2h(w0) * u2h(h0);
    a2 += u2h(w1) * u2h(h1);
    a2 += u2h(w2) * u2h(h2);
    a2 += u2h(w3) * u2h(h3);
    h2_t b2h = u2h(w4) * u2h(h4);
    b2h += u2h(w5) * u2h(h5);
    b2h += u2h(w6) * u2h(h6);
    b2h += u2h(w7) * u2h(h7);
    a2 += b2h;
    ax += (float)a2[0];
    ay += (float)a2[1];
  }
  float2 b2 = ((const float2*)b)[lane];
  float ox = fmaxf(ax + b2.x, 0.f);
  float oy = fmaxf(ay + b2.y, 0.f);
  if (outF)
    ((float2*)outF)[(size_t)dl * 64 + lane] = make_float2(ox, oy);
  else
    ((unsigned*)outB)[(size_t)dl * 64 + lane] = packh2(ox, oy);
}

__global__ void group_bounds(const int* __restrict__ batch, int* __restrict__ gs, int* __restrict__ ge, int n) {
  int i = blockIdx.x * 256 + threadIdx.x;
  if (i >= n) return;
  int b = batch[i];
  if (i == 0 || batch[i - 1] != b) gs[b] = i;
  if (i == n - 1 || batch[i + 1] != b) ge[b] = i + 1;
}

// per-group max & mean; 4 waves split rows, LDS combine
__global__ __launch_bounds__(256) void pool_kernel(const unsigned short* __restrict__ X,
                                                   const int* __restrict__ gs, const int* __restrict__ ge,
                                                   float* __restrict__ x123) {
  __shared__ float2 mxs[4][64];
  __shared__ float2 sms[4][64];
  int g = blockIdx.x;
  int wv = threadIdx.x >> 6;
  int p = threadIdx.x & 63;
  int beg = gs[g], end = ge[g];
  int cnt = end - beg;
  const unsigned* X2 = (const unsigned*)X;
  float mx0 = -FLT_MAX, mx1 = -FLT_MAX, sm0 = 0.f, sm1 = 0.f;
  for (int i = beg + wv; i < end; i += 4) {
    h2_t v = u2h(X2[(size_t)i * 64 + p]);
    float a = (float)v[0], b = (float)v[1];
    mx0 = fmaxf(mx0, a);
    mx1 = fmaxf(mx1, b);
    sm0 += a;
    sm1 += b;
  }
  mxs[wv][p] = make_float2(mx0, mx1);
  sms[wv][p] = make_float2(sm0, sm1);
  __syncthreads();
  if (threadIdx.x < 64 && cnt > 0) {
#pragma unroll
    for (int k = 1; k < 4; ++k) {
      float2 m2 = mxs[k][p], s2 = sms[k][p];
      mx0 = fmaxf(mx0, m2.x);
      mx1 = fmaxf(mx1, m2.y);
      sm0 += s2.x;
      sm1 += s2.y;
    }
    float inv = 1.f / (float)cnt;
    float* xg = x123 + (size_t)g * 256;
    xg[2 * p] += mx0;
    xg[2 * p + 1] += mx1;
    xg[128 + 2 * p] += sm0 * inv;
    xg[128 + 2 * p + 1] += sm1 * inv;
  }
}

// xDP = relu(x123 @ lin1_W + lin1_b), fp16 out
__global__ __launch_bounds__(128) void lin1_kernel(const float* __restrict__ x123, const float* __restrict__ W,
                                                   const float* __restrict__ b, unsigned short* __restrict__ xb) {
  __shared__ float row[256];
  int g = blockIdx.x;
  int c = threadIdx.x;
  row[c] = x123[(size_t)g * 256 + c];
  row[c + 128] = x123[(size_t)g * 256 + 128 + c];
  __syncthreads();
  float acc = b[c];
#pragma unroll 8
  for (int k = 0; k < 256; ++k) acc = fmaf(row[k], W[k * 128 + c], acc);
  _Float16 hv = (_Float16)fmaxf(acc, 0.f);
  xb[(size_t)g * D + c] = __builtin_bit_cast(unsigned short, hv);
}

__global__ void xse_kernel(const float* __restrict__ emb, const int* __restrict__ x_ids,
                           const int* __restrict__ nDrugPtr, int nProtein, unsigned short* __restrict__ xb) {
  int idx = blockIdx.x * 256 + threadIdx.x;
  int r = idx >> 6, lane = idx & 63;
  int off = nDrugPtr[0] + nProtein;
  int id = x_ids[off + r];
  float2 v = ((const float2*)(emb + (size_t)id * D))[lane];
  ((unsigned*)xb)[(size_t)(G_GROUPS + r) * 64 + lane] = packh2(v.x, v.y);
}

__global__ void out_gather(const float* __restrict__ xb, const int* __restrict__ dn, const int* __restrict__ sn,
                           float* __restrict__ out) {
  int idx = blockIdx.x * 256 + threadIdx.x;
  int r = idx >> 6, lane = idx & 63;
  int s = (r < 1000) ? dn[r] : (r < 6000) ? sn[r - 1000] : (r - 6000);
  ((float2*)out)[(size_t)idx] = ((const float2*)(xb + (size_t)s * D))[lane];
}

extern "C" void kernel_launch(void* const* d_in, const int* in_sizes, int n_in, void* d_out, int out_size,
                              void* d_ws, size_t ws_size, hipStream_t stream) {
  const int* x_ids = (const int*)d_in[0];
  const int* drugE = (const int*)d_in[1];
  const int* drugNodes = (const int*)d_in[3];
  const int* seNodes = (const int*)d_in[4];
  int nProtein = in_sizes[5];
  const int* atom_x = (const int*)d_in[7];
  const int* atomE = (const int*)d_in[8];
  const int* atom_batch = (const int*)d_in[9];
  const int* nDrugPtr = (const int*)d_in[10];
  const float* emb = (const float*)d_in[11];
  const float* gatW[3] = {(const float*)d_in[12], (const float*)d_in[17], (const float*)d_in[22]};
  const float* attS[3] = {(const float*)d_in[13], (const float*)d_in[18], (const float*)d_in[23]};
  const float* attD[3] = {(const float*)d_in[14], (const float*)d_in[19], (const float*)d_in[24]};
  const float* gatB[3] = {(const float*)d_in[15], (const float*)d_in[20], (const float*)d_in[25]};
  const float* poolP[3] = {(const float*)d_in[16], (const float*)d_in[21], (const float*)d_in[26]};
  const float* lin1_W = (const float*)d_in[27];
  const float* lin1_b = (const float*)d_in[28];
  const float* gcn1_W = (const float*)d_in[29];
  const float* gcn1_b = (const float*)d_in[30];
  const float* gcn2_W = (const float*)d_in[31];
  const float* gcn2_b = (const float*)d_in[32];
  float* out = (float*)d_out;
  (void)n_in; (void)out_size; (void)ws_size;

  const int MAXX = E_ALL + 8 * N_ALL + 64;  // padded entry upper bound (+slack for scalar over-read)

  char* ws = (char*)d_ws;
  size_t off = 0;
  auto alloc = [&](size_t bytes) -> char* {
    char* p = ws + off;
    off += (bytes + 255) & ~(size_t)255;
    return p;
  };
  unsigned short* bufA = (unsigned short*)alloc((size_t)N_ATOMS * D * 2);  // xa (fp16)
  unsigned short* bufB = (unsigned short*)alloc((size_t)N_ATOMS * D * 2);  // h  (fp16)
  float* hs = (float*)alloc((size_t)N_ATOMS * 4);
  float* hd = (float*)alloc((size_t)N_ATOMS * 4);
  int* csx = (int*)alloc((size_t)MAXX * 4);
  unsigned* wts = (unsigned*)alloc((size_t)MAXX * 4);
  unsigned* wtsG = (unsigned*)alloc((size_t)MAXX * 4);
  int* rank = (int*)alloc((size_t)E_ALL * 4);
  float* x123 = (float*)alloc((size_t)G_GROUPS * 256 * 4);
  unsigned short* xb1 = (unsigned short*)alloc((size_t)N_BIG * D * 2);
  unsigned short* xb2 = (unsigned short*)alloc((size_t)N_BIG * D * 2);
  float* xbF = (float*)alloc((size_t)N_BIG * D * 4);
  unsigned short* Wsplit = (unsigned short*)alloc((size_t)5 * 16384 * 2);
  int* rpx = (int*)alloc((size_t)(N_ALL + 2) * 4);
  int* deg = (int*)alloc((size_t)N_ALL * 4);
  int* cntp = (int*)alloc((size_t)N_ALL * 4);
  float* disB = (float*)alloc((size_t)N_BIG * 4);
  int* gs = (int*)alloc((size_t)G_GROUPS * 4);
  int* ge = (int*)alloc((size_t)G_GROUPS * 4);
  int* bsums = (int*)alloc(256 * 4);
  float* pn = (float*)alloc(256);

  const int* asrc = atomE;
  const int* adst = atomE + E_ATOMS;
  const int* dsrc = drugE;
  const int* ddst = drugE + E_BIG;

  // ---- prep (weight fp16 + pool norms) ----
  prep_kernel<<<6, 256, 0, stream>>>(gatW[0], gatW[1], gatW[2], gcn1_W, gcn2_W, Wsplit, poolP[0], poolP[1],
                                     poolP[2], pn);

  // ---- merged CSR (rank-based, padded to multiple of 8) ----
  hipMemsetAsync(deg, 0, (size_t)N_ALL * 4, stream);
  count_all<<<ceil_div(E_ALL, 256), 256, 0, stream>>>(adst, ddst, deg, rank);
  post_count<<<ceil_div(N_ALL, 256), 256, 0, stream>>>(deg, cntp, disB);
  scan_phase1<<<ceil_div(N_ALL, 1024), 256, 0, stream>>>(cntp, rpx, bsums, N_ALL);
  scan_phase2<<<1, 256, 0, stream>>>(bsums, rpx + N_ALL, ceil_div(N_ALL, 1024));
  scan_phase3<<<ceil_div(N_ALL, 256), 256, 0, stream>>>(rpx, bsums, N_ALL);
  fill_csx<<<ceil_div(E_ALL, 256), 256, 0, stream>>>(asrc, adst, dsrc, ddst, rpx, rank, csx);
  fill_pad<<<ceil_div(N_ALL, 256), 256, 0, stream>>>(deg, rpx, csx);
  gcn_weights<<<ceil_div(N_BIG, 256), 256, 0, stream>>>(rpx, deg, csx, disB, wtsG, N_BIG);

  // ---- group ranges ----
  hipMemsetAsync(gs, 0, (size_t)G_GROUPS * 4, stream);
  hipMemsetAsync(ge, 0, (size_t)G_GROUPS * 4, stream);
  group_bounds<<<ceil_div(N_ATOMS, 256), 256, 0, stream>>>(atom_batch, gs, ge, N_ATOMS);

  hipMemsetAsync(x123, 0, (size_t)G_GROUPS * 256 * 4, stream);

  // ---- 3 GAT layers (layer 0 gathers A-rows directly from the fp32 emb table) ----
  for (int L = 0; L < 3; ++L) {
    gemm_f16<<<ceil_div(N_ATOMS, 256), 256, 0, stream>>>(bufA, emb, (L == 0) ? atom_x : nullptr,
                                                         Wsplit + (size_t)L * 16384, bufB, hs, hd, attS[L],
                                                         attD[L], N_ATOMS);
    edge_weights<<<ceil_div(N_ATOMS, 256), 256, 0, stream>>>(hs, hd, rpx, deg, csx, wts, N_ATOMS);
    gat_gather<<<ceil_div(N_ATOMS / 2 * 64, 256), 256, 0, stream>>>(bufB, rpx, csx, wts, gatB[L], poolP[L],
                                                                    pn + L, bufA, N_ATOMS);
    pool_kernel<<<G_GROUPS, 256, 0, stream>>>(bufA, gs, ge, x123);
  }

  // ---- MLP + big-graph node features ----
  lin1_kernel<<<G_GROUPS, 128, 0, stream>>>(x123, lin1_W, lin1_b, xb1);
  xse_kernel<<<(N_BIG - G_GROUPS) * 64 / 256, 256, 0, stream>>>(emb, x_ids, nDrugPtr, nProtein, xb1);

  // ---- 2 GCN layers ----
  gemm_f16<<<ceil_div(N_BIG, 256), 256, 0, stream>>>(xb1, nullptr, nullptr, Wsplit + (size_t)3 * 16384, bufB,
                                                     nullptr, nullptr, nullptr, nullptr, N_BIG);
  gcn_gather<<<N_BIG * 64 / 256, 256, 0, stream>>>(bufB, rpx, csx, wtsG, gcn1_b, xb2, nullptr, N_BIG);
  gemm_f16<<<ceil_div(N_BIG, 256), 256, 0, stream>>>(xb2, nullptr, nullptr, Wsplit + (size_t)4 * 16384, bufB,
                                                     nullptr, nullptr, nullptr, nullptr, N_BIG);
  gcn_gather<<<N_BIG * 64 / 256, 256, 0, stream>>>(bufB, rpx, csx, wtsG, gcn2_b, nullptr, xbF, N_BIG);

  // ---- outputs ----
  out_gather<<<13000 * 64 / 256, 256, 0, stream>>>(xbF, drugNodes, seNodes, out);
}

// Round 20
// 462.731 us; speedup vs baseline: 1.1268x; 1.0743x over previous
//
#include <hip/hip_runtime.h>
#include <cfloat>
#include <cmath>

#define D 128
#define N_ATOMS 200000
#define E_ATOMS 800000
#define G_GROUPS 2000
#define N_BIG 7000
#define E_BIG 200000
#define N_ALL (N_ATOMS + N_BIG)
#define E_ALL (E_ATOMS + E_BIG)

static inline int ceil_div(int a, int b) { return (a + b - 1) / b; }

typedef __attribute__((ext_vector_type(8))) _Float16 f16x8;
typedef __attribute__((ext_vector_type(2))) _Float16 h2_t;
typedef __attribute__((ext_vector_type(4))) float f32x4;

__device__ inline h2_t u2h(unsigned u) { return __builtin_bit_cast(h2_t, u); }
__device__ inline unsigned h2u(h2_t h) { return __builtin_bit_cast(unsigned, h); }
__device__ inline unsigned packh2(float x, float y) {
  h2_t h;
  h[0] = (_Float16)x;
  h[1] = (_Float16)y;
  return h2u(h);
}
__device__ inline float leaky(float e) { return fmaxf(e, 0.2f * e); }
__device__ inline float fast_tanh(float x) {
  float cx = fminf(fmaxf(x, -15.f), 15.f);
  float t = __expf(2.f * cx);
  return (t - 1.f) * __frcp_rn(t + 1.f);
}

// ---------------- CSR build (both graphs merged, rank-based, atomic only in count) --------
__global__ void count_all(const int* __restrict__ adst, const int* __restrict__ ddst, int* __restrict__ deg,
                          int* __restrict__ rank) {
  int i = blockIdx.x * 256 + threadIdx.x;
  if (i < E_ATOMS)
    rank[i] = atomicAdd(&deg[adst[i]], 1);
  else if (i < E_ALL)
    rank[i] = atomicAdd(&deg[N_ATOMS + ddst[i - E_ATOMS]], 1);
}

__global__ void fill_csx(const int* __restrict__ asrc, const int* __restrict__ adst,
                         const int* __restrict__ dsrc, const int* __restrict__ ddst,
                         const int* __restrict__ rpx, const int* __restrict__ rank, int* __restrict__ csx) {
  int i = blockIdx.x * 256 + threadIdx.x;
  if (i < E_ATOMS) {
    csx[rpx[adst[i]] + rank[i]] = asrc[i];
  } else if (i < E_ALL) {
    int k = i - E_ATOMS;
    csx[rpx[N_ATOMS + ddst[k]] + rank[i]] = dsrc[k];
  }
}

// self entry + pad entries (src = self) for every node
__global__ void fill_pad(const int* __restrict__ deg, const int* __restrict__ rpx, int* __restrict__ csx) {
  int d = blockIdx.x * 256 + threadIdx.x;
  if (d >= N_ALL) return;
  int dg = deg[d];
  int b = rpx[d], e = rpx[d + 1];
  int sv = (d < N_ATOMS) ? d : d - N_ATOMS;  // big-graph srcs are local indices
  for (int j = b + dg; j < e; ++j) csx[j] = sv;
}

// cntp for all nodes + dis for big-graph nodes (merged)
__global__ void post_count(const int* __restrict__ deg, int* __restrict__ cntp, float* __restrict__ dis) {
  int i = blockIdx.x * 256 + threadIdx.x;
  if (i < N_ALL) cntp[i] = (deg[i] + 8) & ~7;  // (deg + 1 self) padded to multiple of 8
  if (i < N_BIG) dis[i] = 1.f / sqrtf((float)(deg[N_ATOMS + i] + 1));
}

__global__ __launch_bounds__(256) void scan_phase1(const int* __restrict__ in, int* __restrict__ out,
                                                   int* __restrict__ bsums, int n) {
  __shared__ int lds[256];
  int t = threadIdx.x;
  int base = blockIdx.x * 1024;
  int v[4];
  int s = 0;
#pragma unroll
  for (int j = 0; j < 4; ++j) {
    int i = base + t * 4 + j;
    v[j] = (i < n) ? in[i] : 0;
    s += v[j];
  }
  lds[t] = s;
  __syncthreads();
  for (int off = 1; off < 256; off <<= 1) {
    int x = (t >= off) ? lds[t - off] : 0;
    __syncthreads();
    lds[t] += x;
    __syncthreads();
  }
  int excl = lds[t] - s;
  if (t == 255) bsums[blockIdx.x] = lds[255];
  int run = excl;
#pragma unroll
  for (int j = 0; j < 4; ++j) {
    int i = base + t * 4 + j;
    if (i < n) out[i] = run;
    run += v[j];
  }
}

__global__ __launch_bounds__(256) void scan_phase2(int* __restrict__ bsums, int* __restrict__ total_out, int nb) {
  __shared__ int lds[256];
  int t = threadIdx.x;
  int s = (t < nb) ? bsums[t] : 0;
  lds[t] = s;
  __syncthreads();
  for (int off = 1; off < 256; off <<= 1) {
    int x = (t >= off) ? lds[t - off] : 0;
    __syncthreads();
    lds[t] += x;
    __syncthreads();
  }
  if (t < nb) bsums[t] = lds[t] - s;
  if (t == 255) total_out[0] = lds[255];
}

__global__ void scan_phase3(int* __restrict__ out, const int* __restrict__ bsums, int n) {
  int i = blockIdx.x * 256 + threadIdx.x;
  if (i < n) out[i] += bsums[i >> 10];
}

// ---------------- prep: W -> swizzled fp16 (transposed) + inv pool-norms ----------------
__global__ __launch_bounds__(256) void prep_kernel(const float* __restrict__ W0, const float* __restrict__ W1,
                                                   const float* __restrict__ W2, const float* __restrict__ W3,
                                                   const float* __restrict__ W4, unsigned short* __restrict__ Wsplit,
                                                   const float* __restrict__ p0, const float* __restrict__ p1,
                                                   const float* __restrict__ p2, float* __restrict__ pn) {
  int b = blockIdx.x;
  if (b < 5) {
    const float* W = (b == 0) ? W0 : (b == 1) ? W1 : (b == 2) ? W2 : (b == 3) ? W3 : W4;
    unsigned short* dstH = Wsplit + (size_t)b * 16384;
    int t = threadIdx.x;
    int col = t & 127;
    int half = t >> 7;
#pragma unroll
    for (int kg = 0; kg < 8; ++kg) {
      int k0 = kg * 16 + half * 8;
      f16x8 vh;
#pragma unroll
      for (int j = 0; j < 8; ++j) vh[j] = (_Float16)W[(k0 + j) * 128 + col];
      int byte_off = (col * 256 + k0 * 2) ^ ((col & 7) << 4);
      *(f16x8*)((char*)dstH + byte_off) = vh;
    }
  } else {
    int t = threadIdx.x;
    int g = t >> 6, lane = t & 63;
    if (g < 3) {
      const float* p = (g == 0) ? p0 : (g == 1) ? p1 : p2;
      float2 v = ((const float2*)p)[lane];
      float s = v.x * v.x + v.y * v.y;
#pragma unroll
      for (int off = 32; off; off >>= 1) s += __shfl_xor(s, off);
      if (lane == 0) pn[g] = 1.f / sqrtf(s);
    }
  }
}

// ---------------- MFMA GEMM: H[M,128] = A[M,128](fp16) @ W(fp16, swizzled) ----------
// 4 waves x 32 rows = 128 rows/block (fine-grained blocks for occupancy).
// All A fragments prefetched before the MFMA loop.
// If ids != nullptr, A-rows are gathered from the fp32 table embA[ids[row]].
__global__ __launch_bounds__(256, 4) void gemm_f16(const unsigned short* __restrict__ A,
                                                   const float* __restrict__ embA, const int* __restrict__ ids,
                                                   const unsigned short* __restrict__ Wsp,
                                                   unsigned short* __restrict__ H, float* __restrict__ hs,
                                                   float* __restrict__ hd, const float* __restrict__ aS,
                                                   const float* __restrict__ aD, int M) {
  __shared__ unsigned short Wl[16384];  // transposed [col][k], XOR-swizzled (32 KB)
  int t = threadIdx.x;
  {
    const uint4* src = (const uint4*)Wsp;
    uint4* dst = (uint4*)Wl;
#pragma unroll
    for (int i = 0; i < 8; ++i) dst[t + i * 256] = src[t + i * 256];
  }
  int wave = t >> 6, lane = t & 63;
  int lr = lane & 15, lq = lane >> 4;
  int row0 = blockIdx.x * 128 + wave * 32;
  // prefetch all A fragments [ks][rt] — 8 (or 16) independent loads in flight
  f16x8 Af[4][2];
  if (ids) {
    int rid[2];
#pragma unroll
    for (int rt = 0; rt < 2; ++rt) {
      int row = row0 + rt * 16 + lr;
      rid[rt] = (row < M) ? ids[row] : 0;
    }
#pragma unroll
    for (int ks = 0; ks < 4; ++ks)
#pragma unroll
      for (int rt = 0; rt < 2; ++rt) {
        int row = row0 + rt * 16 + lr;
        if (row < M) {
          const float* src = embA + (size_t)rid[rt] * D + ks * 32 + lq * 8;
          float4 v0 = *(const float4*)src;
          float4 v1 = *(const float4*)(src + 4);
          f16x8 a;
          a[0] = (_Float16)v0.x; a[1] = (_Float16)v0.y; a[2] = (_Float16)v0.z; a[3] = (_Float16)v0.w;
          a[4] = (_Float16)v1.x; a[5] = (_Float16)v1.y; a[6] = (_Float16)v1.z; a[7] = (_Float16)v1.w;
          Af[ks][rt] = a;
        } else {
          Af[ks][rt] = (f16x8){0, 0, 0, 0, 0, 0, 0, 0};
        }
      }
  } else {
#pragma unroll
    for (int ks = 0; ks < 4; ++ks)
#pragma unroll
      for (int rt = 0; rt < 2; ++rt) {
        int row = row0 + rt * 16 + lr;
        if (row < M) {
          Af[ks][rt] = *(const f16x8*)(A + (size_t)row * D + ks * 32 + lq * 8);
        } else {
          Af[ks][rt] = (f16x8){0, 0, 0, 0, 0, 0, 0, 0};
        }
      }
  }
  __syncthreads();
  f32x4 acc[2][8];
#pragma unroll
  for (int rt = 0; rt < 2; ++rt)
#pragma unroll
    for (int ct = 0; ct < 8; ++ct) acc[rt][ct] = (f32x4){0.f, 0.f, 0.f, 0.f};

#pragma unroll
  for (int ks = 0; ks < 4; ++ks) {
    int k8 = ks * 32 + lq * 8;
#pragma unroll
    for (int ct = 0; ct < 8; ++ct) {
      int col = ct * 16 + lr;
      int byte_off = (col * 256 + k8 * 2) ^ ((col & 7) << 4);
      f16x8 Bh = *(f16x8*)((char*)Wl + byte_off);
#pragma unroll
      for (int rt = 0; rt < 2; ++rt)
        acc[rt][ct] = __builtin_amdgcn_mfma_f32_16x16x32_f16(Af[ks][rt], Bh, acc[rt][ct], 0, 0, 0);
    }
  }
  // C/D layout: col = lane&15, row = (lane>>4)*4 + i
#pragma unroll
  for (int rt = 0; rt < 2; ++rt)
#pragma unroll
    for (int ct = 0; ct < 8; ++ct) {
      int col = ct * 16 + lr;
#pragma unroll
      for (int i = 0; i < 4; ++i) {
        int row = row0 + rt * 16 + lq * 4 + i;
        if (row < M) {
          _Float16 hv = (_Float16)acc[rt][ct][i];
          H[(size_t)row * D + col] = __builtin_bit_cast(unsigned short, hv);
        }
      }
    }
  if (aS) {
    float sA[8], sD[8];
#pragma unroll
    for (int ct = 0; ct < 8; ++ct) {
      sA[ct] = aS[ct * 16 + lr];
      sD[ct] = aD[ct * 16 + lr];
    }
#pragma unroll
    for (int rt = 0; rt < 2; ++rt)
#pragma unroll
      for (int i = 0; i < 4; ++i) {
        float ps = 0.f, pd = 0.f;
#pragma unroll
        for (int ct = 0; ct < 8; ++ct) {
          ps = fmaf(acc[rt][ct][i], sA[ct], ps);
          pd = fmaf(acc[rt][ct][i], sD[ct], pd);
        }
#pragma unroll
        for (int off = 1; off < 16; off <<= 1) {
          ps += __shfl_xor(ps, off);
          pd += __shfl_xor(pd, off);
        }
        int row = row0 + rt * 16 + lq * 4 + i;
        if (lr == 0 && row < M) {
          hs[row] = ps;
          hd[row] = pd;
        }
      }
  }
}

// ---------------- GAT edge weights: single-pass + L1-hot normalize (pads = 0) ------------
// Writes NORMALIZED weights (w/z) as packed {w,w} fp16.
__global__ void edge_weights(const float* __restrict__ hs, const float* __restrict__ hd,
                             const int* __restrict__ rpx, const int* __restrict__ deg,
                             const int* __restrict__ csx, unsigned* __restrict__ wts, int N) {
  int d = blockIdx.x * 256 + threadIdx.x;
  if (d >= N) return;
  int b = rpx[d];
  int cnt = rpx[d + 1] - b;
  int dg = deg[d];
  float hdd = hd[d];
  float* wf = (float*)wts;
  float z = 0.f;
  for (int j = 0; j < dg; ++j) {
    float w = __expf(leaky(hs[csx[b + j]] + hdd));
    z += w;
    wf[b + j] = w;
  }
  float wself = __expf(leaky(hs[d] + hdd));
  wf[b + dg] = wself;
  z += wself;
  float iz = 1.f / z;
  for (int j = 0; j <= dg; ++j) {
    float wn = wf[b + j] * iz;
    wts[b + j] = packh2(wn, wn);
  }
  for (int j = dg + 1; j < cnt; ++j) wts[b + j] = 0;
}

// ---------------- GCN edge weights (feature-independent, built once; pads = 0) ------------
__global__ void gcn_weights(const int* __restrict__ rpx, const int* __restrict__ deg,
                            const int* __restrict__ csx, const float* __restrict__ dis,
                            unsigned* __restrict__ wtsG, int N) {
  int dl = blockIdx.x * 256 + threadIdx.x;
  if (dl >= N) return;
  int d = N_ATOMS + dl;
  int b = rpx[d];
  int cnt = rpx[d + 1] - b;
  int dg = deg[d];
  float dd = dis[dl];
  for (int j = 0; j < dg; ++j) {
    float w = dis[csx[b + j]] * dd;
    wtsG[b + j] = packh2(w, w);
  }
  wtsG[b + dg] = packh2(dd * dd, dd * dd);
  for (int j = dg + 1; j < cnt; ++j) wtsG[b + j] = 0;
}

// ---------------- GAT gather: 2 dsts per wave (32 lanes each), 16 rows in flight ----------
__global__ __launch_bounds__(256) void gat_gather(const unsigned short* __restrict__ H,
                                                  const int* __restrict__ rpx, const int* __restrict__ csx,
                                                  const unsigned* __restrict__ wts,
                                                  const float* __restrict__ bias,
                                                  const float* __restrict__ poolP, const float* __restrict__ pnL,
                                                  unsigned short* __restrict__ Xout, int N) {
  int wid = (blockIdx.x * 256 + threadIdx.x) >> 6;
  int d0 = __builtin_amdgcn_readfirstlane(wid << 1);
  if (d0 >= N) return;
  int lane = threadIdx.x & 63;
  int half = lane >> 5;
  int hl = lane & 31;
  int rb0 = rpx[d0];
  int rb1 = rpx[d0 + 1];
  int rb2 = rpx[d0 + 2];
  int cnt0 = rb1 - rb0;          // multiples of 8
  int cnt1 = rb2 - rb1;
  int cnt_h = half ? cnt1 : cnt0;
  const uint2* H2 = (const uint2*)H;  // 32 uint2 per row (4 channels per lane)
  float a0 = 0.f, a1 = 0.f, a2 = 0.f, a3 = 0.f;
  for (int i = 0; i < cnt_h; i += 8) {
    int ib = __builtin_amdgcn_readfirstlane(i);
    // scalar streams for both halves (uniform addresses)
    int sA[8], sB[8];
    unsigned wA[8], wB[8];
#pragma unroll
    for (int j = 0; j < 8; ++j) {
      sA[j] = csx[rb0 + ib + j];
      sB[j] = csx[rb1 + ib + j];
      wA[j] = wts[rb0 + ib + j];
      wB[j] = wts[rb1 + ib + j];
    }
    h2_t acc0 = (h2_t){(_Float16)0.f, (_Float16)0.f};
    h2_t acc1 = acc0;
#pragma unroll
    for (int j = 0; j < 8; ++j) {
      int sj = half ? sB[j] : sA[j];
      unsigned wj = half ? wB[j] : wA[j];
      uint2 hv = H2[(size_t)sj * 32 + hl];
      h2_t wh = u2h(wj);
      acc0 += wh * u2h(hv.x);
      acc1 += wh * u2h(hv.y);
    }
    a0 += (float)acc0[0];
    a1 += (float)acc0[1];
    a2 += (float)acc1[0];
    a3 += (float)acc1[1];
  }
  float4 b4 = ((const float4*)bias)[hl];
  a0 = fmaxf(a0 + b4.x, 0.f);
  a1 = fmaxf(a1 + b4.y, 0.f);
  a2 = fmaxf(a2 + b4.z, 0.f);
  a3 = fmaxf(a3 + b4.w, 0.f);
  float4 p4 = ((const float4*)poolP)[hl];
  float dot = a0 * p4.x + a1 * p4.y + a2 * p4.z + a3 * p4.w;
#pragma unroll
  for (int off = 16; off; off >>= 1) dot += __shfl_xor(dot, off);  // within each half
  float sc = fast_tanh(dot * pnL[0]);
  uint2 o;
  o.x = packh2(a0 * sc, a1 * sc);
  o.y = packh2(a2 * sc, a3 * sc);
  ((uint2*)Xout)[(size_t)(d0 + half) * 32 + hl] = o;
}

// ---------------- GCN gather: 8 rows in flight; fp16 or fp32 out ----------------
__global__ __launch_bounds__(256) void gcn_gather(const unsigned short* __restrict__ Y,
                                                  const int* __restrict__ rpx, const int* __restrict__ csx,
                                                  const unsigned* __restrict__ wtsG, const float* __restrict__ b,
                                                  unsigned short* __restrict__ outB, float* __restrict__ outF,
                                                  int N) {
  int wid = (blockIdx.x * 256 + threadIdx.x) >> 6;
  int dl = __builtin_amdgcn_readfirstlane(wid);
  if (dl >= N) return;
  int lane = threadIdx.x & 63;
  int rb = rpx[N_ATOMS + dl];
  int cnt = rpx[N_ATOMS + dl + 1] - rb;
  const unsigned* Y2 = (const unsigned*)Y;
  float ax = 0.f, ay = 0.f;
  for (int i = 0; i < cnt; i += 8) {
    int s0 = csx[rb + i + 0], s1 = csx[rb + i + 1], s2 = csx[rb + i + 2], s3 = csx[rb + i + 3];
    int s4 = csx[rb + i + 4], s5 = csx[rb + i + 5], s6 = csx[rb + i + 6], s7 = csx[rb + i + 7];
    unsigned w0 = wtsG[rb + i + 0], w1 = wtsG[rb + i + 1], w2 = wtsG[rb + i + 2], w3 = wtsG[rb + i + 3];
    unsigned w4 = wtsG[rb + i + 4], w5 = wtsG[rb + i + 5], w6 = wtsG[rb + i + 6], w7 = wtsG[rb + i + 7];
    unsigned h0 = Y2[(size_t)s0 * 64 + lane];
    unsigned h1 = Y2[(size_t)s1 * 64 + lane];
    unsigned h2 = Y2[(size_t)s2 * 64 + lane];
    unsigned h3 = Y2[(size_t)s3 * 64 + lane];
    unsigned h4 = Y2[(size_t)s4 * 64 + lane];
    unsigned h5 = Y2[(size_t)s5 * 64 + lane];
    unsigned h6 = Y2[(size_t)s6 * 64 + lane];
    unsigned h7 = Y2[(size_t)s7 * 64 + lane];
    h2_t a2 = u2h(w0) * u2h(h0);
    a2 += u2h(w1) * u2h(h1);
    a2 += u2h(w2) * u2h(h2);
    a2 += u2h(w3) * u2h(h3);
    h2_t b2h = u2h(w4) * u2h(h4);
    b2h += u2h(w5) * u2h(h5);
    b2h += u2h(w6) * u2h(h6);
    b2h += u2h(w7) * u2h(h7);
    a2 += b2h;
    ax += (float)a2[0];
    ay += (float)a2[1];
  }
  float2 b2 = ((const float2*)b)[lane];
  float ox = fmaxf(ax + b2.x, 0.f);
  float oy = fmaxf(ay + b2.y, 0.f);
  if (outF)
    ((float2*)outF)[(size_t)dl * 64 + lane] = make_float2(ox, oy);
  else
    ((unsigned*)outB)[(size_t)dl * 64 + lane] = packh2(ox, oy);
}

__global__ void group_bounds(const int* __restrict__ batch, int* __restrict__ gs, int* __restrict__ ge, int n) {
  int i = blockIdx.x * 256 + threadIdx.x;
  if (i >= n) return;
  int b = batch[i];
  if (i == 0 || batch[i - 1] != b) gs[b] = i;
  if (i == n - 1 || batch[i + 1] != b) ge[b] = i + 1;
}

// per-group max & mean; 4 waves split rows, LDS combine
__global__ __launch_bounds__(256) void pool_kernel(const unsigned short* __restrict__ X,
                                                   const int* __restrict__ gs, const int* __restrict__ ge,
                                                   float* __restrict__ x123) {
  __shared__ float2 mxs[4][64];
  __shared__ float2 sms[4][64];
  int g = blockIdx.x;
  int wv = threadIdx.x >> 6;
  int p = threadIdx.x & 63;
  int beg = gs[g], end = ge[g];
  int cnt = end - beg;
  const unsigned* X2 = (const unsigned*)X;
  float mx0 = -FLT_MAX, mx1 = -FLT_MAX, sm0 = 0.f, sm1 = 0.f;
  for (int i = beg + wv; i < end; i += 4) {
    h2_t v = u2h(X2[(size_t)i * 64 + p]);
    float a = (float)v[0], b = (float)v[1];
    mx0 = fmaxf(mx0, a);
    mx1 = fmaxf(mx1, b);
    sm0 += a;
    sm1 += b;
  }
  mxs[wv][p] = make_float2(mx0, mx1);
  sms[wv][p] = make_float2(sm0, sm1);
  __syncthreads();
  if (threadIdx.x < 64 && cnt > 0) {
#pragma unroll
    for (int k = 1; k < 4; ++k) {
      float2 m2 = mxs[k][p], s2 = sms[k][p];
      mx0 = fmaxf(mx0, m2.x);
      mx1 = fmaxf(mx1, m2.y);
      sm0 += s2.x;
      sm1 += s2.y;
    }
    float inv = 1.f / (float)cnt;
    float* xg = x123 + (size_t)g * 256;
    xg[2 * p] += mx0;
    xg[2 * p + 1] += mx1;
    xg[128 + 2 * p] += sm0 * inv;
    xg[128 + 2 * p + 1] += sm1 * inv;
  }
}

// xDP = relu(x123 @ lin1_W + lin1_b), fp16 out
__global__ __launch_bounds__(128) void lin1_kernel(const float* __restrict__ x123, const float* __restrict__ W,
                                                   const float* __restrict__ b, unsigned short* __restrict__ xb) {
  __shared__ float row[256];
  int g = blockIdx.x;
  int c = threadIdx.x;
  row[c] = x123[(size_t)g * 256 + c];
  row[c + 128] = x123[(size_t)g * 256 + 128 + c];
  __syncthreads();
  float acc = b[c];
#pragma unroll 8
  for (int k = 0; k < 256; ++k) acc = fmaf(row[k], W[k * 128 + c], acc);
  _Float16 hv = (_Float16)fmaxf(acc, 0.f);
  xb[(size_t)g * D + c] = __builtin_bit_cast(unsigned short, hv);
}

__global__ void xse_kernel(const float* __restrict__ emb, const int* __restrict__ x_ids,
                           const int* __restrict__ nDrugPtr, int nProtein, unsigned short* __restrict__ xb) {
  int idx = blockIdx.x * 256 + threadIdx.x;
  int r = idx >> 6, lane = idx & 63;
  int off = nDrugPtr[0] + nProtein;
  int id = x_ids[off + r];
  float2 v = ((const float2*)(emb + (size_t)id * D))[lane];
  ((unsigned*)xb)[(size_t)(G_GROUPS + r) * 64 + lane] = packh2(v.x, v.y);
}

__global__ void out_gather(const float* __restrict__ xb, const int* __restrict__ dn, const int* __restrict__ sn,
                           float* __restrict__ out) {
  int idx = blockIdx.x * 256 + threadIdx.x;
  int r = idx >> 6, lane = idx & 63;
  int s = (r < 1000) ? dn[r] : (r < 6000) ? sn[r - 1000] : (r - 6000);
  ((float2*)out)[(size_t)idx] = ((const float2*)(xb + (size_t)s * D))[lane];
}

extern "C" void kernel_launch(void* const* d_in, const int* in_sizes, int n_in, void* d_out, int out_size,
                              void* d_ws, size_t ws_size, hipStream_t stream) {
  const int* x_ids = (const int*)d_in[0];
  const int* drugE = (const int*)d_in[1];
  const int* drugNodes = (const int*)d_in[3];
  const int* seNodes = (const int*)d_in[4];
  int nProtein = in_sizes[5];
  const int* atom_x = (const int*)d_in[7];
  const int* atomE = (const int*)d_in[8];
  const int* atom_batch = (const int*)d_in[9];
  const int* nDrugPtr = (const int*)d_in[10];
  const float* emb = (const float*)d_in[11];
  const float* gatW[3] = {(const float*)d_in[12], (const float*)d_in[17], (const float*)d_in[22]};
  const float* attS[3] = {(const float*)d_in[13], (const float*)d_in[18], (const float*)d_in[23]};
  const float* attD[3] = {(const float*)d_in[14], (const float*)d_in[19], (const float*)d_in[24]};
  const float* gatB[3] = {(const float*)d_in[15], (const float*)d_in[20], (const float*)d_in[25]};
  const float* poolP[3] = {(const float*)d_in[16], (const float*)d_in[21], (const float*)d_in[26]};
  const float* lin1_W = (const float*)d_in[27];
  const float* lin1_b = (const float*)d_in[28];
  const float* gcn1_W = (const float*)d_in[29];
  const float* gcn1_b = (const float*)d_in[30];
  const float* gcn2_W = (const float*)d_in[31];
  const float* gcn2_b = (const float*)d_in[32];
  float* out = (float*)d_out;
  (void)n_in; (void)out_size; (void)ws_size;

  const int MAXX = E_ALL + 8 * N_ALL + 64;  // padded entry upper bound (+slack for scalar over-read)

  char* ws = (char*)d_ws;
  size_t off = 0;
  auto alloc = [&](size_t bytes) -> char* {
    char* p = ws + off;
    off += (bytes + 255) & ~(size_t)255;
    return p;
  };
  unsigned short* bufA = (unsigned short*)alloc((size_t)N_ATOMS * D * 2);  // xa (fp16)
  unsigned short* bufB = (unsigned short*)alloc((size_t)N_ATOMS * D * 2);  // h  (fp16)
  float* hs = (float*)alloc((size_t)N_ATOMS * 4);
  float* hd = (float*)alloc((size_t)N_ATOMS * 4);
  int* csx = (int*)alloc((size_t)MAXX * 4);
  unsigned* wts = (unsigned*)alloc((size_t)MAXX * 4);
  unsigned* wtsG = (unsigned*)alloc((size_t)MAXX * 4);
  int* rank = (int*)alloc((size_t)E_ALL * 4);
  float* x123 = (float*)alloc((size_t)G_GROUPS * 256 * 4);
  unsigned short* xb1 = (unsigned short*)alloc((size_t)N_BIG * D * 2);
  unsigned short* xb2 = (unsigned short*)alloc((size_t)N_BIG * D * 2);
  float* xbF = (float*)alloc((size_t)N_BIG * D * 4);
  unsigned short* Wsplit = (unsigned short*)alloc((size_t)5 * 16384 * 2);
  int* rpx = (int*)alloc((size_t)(N_ALL + 2) * 4);
  int* deg = (int*)alloc((size_t)N_ALL * 4);
  int* cntp = (int*)alloc((size_t)N_ALL * 4);
  float* disB = (float*)alloc((size_t)N_BIG * 4);
  int* gs = (int*)alloc((size_t)G_GROUPS * 4);
  int* ge = (int*)alloc((size_t)G_GROUPS * 4);
  int* bsums = (int*)alloc(256 * 4);
  float* pn = (float*)alloc(256);

  const int* asrc = atomE;
  const int* adst = atomE + E_ATOMS;
  const int* dsrc = drugE;
  const int* ddst = drugE + E_BIG;

  // ---- prep (weight fp16 + pool norms) ----
  prep_kernel<<<6, 256, 0, stream>>>(gatW[0], gatW[1], gatW[2], gcn1_W, gcn2_W, Wsplit, poolP[0], poolP[1],
                                     poolP[2], pn);

  // ---- merged CSR (rank-based, padded to multiple of 8) ----
  hipMemsetAsync(deg, 0, (size_t)N_ALL * 4, stream);
  count_all<<<ceil_div(E_ALL, 256), 256, 0, stream>>>(adst, ddst, deg, rank);
  post_count<<<ceil_div(N_ALL, 256), 256, 0, stream>>>(deg, cntp, disB);
  scan_phase1<<<ceil_div(N_ALL, 1024), 256, 0, stream>>>(cntp, rpx, bsums, N_ALL);
  scan_phase2<<<1, 256, 0, stream>>>(bsums, rpx + N_ALL, ceil_div(N_ALL, 1024));
  scan_phase3<<<ceil_div(N_ALL, 256), 256, 0, stream>>>(rpx, bsums, N_ALL);
  fill_csx<<<ceil_div(E_ALL, 256), 256, 0, stream>>>(asrc, adst, dsrc, ddst, rpx, rank, csx);
  fill_pad<<<ceil_div(N_ALL, 256), 256, 0, stream>>>(deg, rpx, csx);
  gcn_weights<<<ceil_div(N_BIG, 256), 256, 0, stream>>>(rpx, deg, csx, disB, wtsG, N_BIG);

  // ---- group ranges ----
  hipMemsetAsync(gs, 0, (size_t)G_GROUPS * 4, stream);
  hipMemsetAsync(ge, 0, (size_t)G_GROUPS * 4, stream);
  group_bounds<<<ceil_div(N_ATOMS, 256), 256, 0, stream>>>(atom_batch, gs, ge, N_ATOMS);

  hipMemsetAsync(x123, 0, (size_t)G_GROUPS * 256 * 4, stream);

  // ---- 3 GAT layers (layer 0 gathers A-rows directly from the fp32 emb table) ----
  for (int L = 0; L < 3; ++L) {
    gemm_f16<<<ceil_div(N_ATOMS, 128), 256, 0, stream>>>(bufA, emb, (L == 0) ? atom_x : nullptr,
                                                         Wsplit + (size_t)L * 16384, bufB, hs, hd, attS[L],
                                                         attD[L], N_ATOMS);
    edge_weights<<<ceil_div(N_ATOMS, 256), 256, 0, stream>>>(hs, hd, rpx, deg, csx, wts, N_ATOMS);
    gat_gather<<<ceil_div(N_ATOMS / 2 * 64, 256), 256, 0, stream>>>(bufB, rpx, csx, wts, gatB[L], poolP[L],
                                                                    pn + L, bufA, N_ATOMS);
    pool_kernel<<<G_GROUPS, 256, 0, stream>>>(bufA, gs, ge, x123);
  }

  // ---- MLP + big-graph node features ----
  lin1_kernel<<<G_GROUPS, 128, 0, stream>>>(x123, lin1_W, lin1_b, xb1);
  xse_kernel<<<(N_BIG - G_GROUPS) * 64 / 256, 256, 0, stream>>>(emb, x_ids, nDrugPtr, nProtein, xb1);

  // ---- 2 GCN layers ----
  gemm_f16<<<ceil_div(N_BIG, 128), 256, 0, stream>>>(xb1, nullptr, nullptr, Wsplit + (size_t)3 * 16384, bufB,
                                                     nullptr, nullptr, nullptr, nullptr, N_BIG);
  gcn_gather<<<N_BIG * 64 / 256, 256, 0, stream>>>(bufB, rpx, csx, wtsG, gcn1_b, xb2, nullptr, N_BIG);
  gemm_f16<<<ceil_div(N_BIG, 128), 256, 0, stream>>>(xb2, nullptr, nullptr, Wsplit + (size_t)4 * 16384, bufB,
                                                     nullptr, nullptr, nullptr, nullptr, N_BIG);
  gcn_gather<<<N_BIG * 64 / 256, 256, 0, stream>>>(bufB, rpx, csx, wtsG, gcn2_b, nullptr, xbF, N_BIG);

  // ---- outputs ----
  out_gather<<<13000 * 64 / 256, 256, 0, stream>>>(xbF, drugNodes, seNodes, out);
}